// Round 15
// baseline (107.074 us; speedup 1.0000x reference)
//
#include <hip/hip_runtime.h>

// MultiHeadAttentionLayer: n=4096, dim=512, h=8, d=64, fp32 in/out.
// R14b: R14 with the cvt_pkrtz type fix (__fp16 vector, not _Float16).
// attn -> bias-init softmax (QK accumulator starts at -m; common path has NO
// pre-exp subtraction; m0=0 finite, rare re-bias when mx>8 biased), pointer-
// increment staging. proj -> RTZ-pack Dekker split. Rest unchanged from R13.

typedef __attribute__((ext_vector_type(8))) short bf16x8;
typedef __attribute__((ext_vector_type(8))) _Float16 f16x8;
typedef __attribute__((ext_vector_type(2))) __fp16 h16x2;
typedef __attribute__((ext_vector_type(4))) float f32x4;
typedef unsigned short u16;

static __device__ __forceinline__ u16 f2bf(float f) {
  union { float f; unsigned u; } v; v.f = f;
  unsigned r = v.u + 0x7fffu + ((v.u >> 16) & 1u);
  return (u16)(r >> 16);
}
static __device__ __forceinline__ float bf2f(u16 h) {
  union { unsigned u; float f; } v; v.u = ((unsigned)h) << 16; return v.f;
}
static __device__ __forceinline__ u16 f2h(float f) {
  union { _Float16 h; u16 u; } v; v.h = (_Float16)f; return v.u;
}
static __device__ __forceinline__ unsigned cvt_pk_bf16(float lo, float hi) {
  unsigned r;
  asm("v_cvt_pk_bf16_f32 %0, %1, %2" : "=v"(r) : "v"(lo), "v"(hi));
  return r;
}
static __device__ __forceinline__ float exp2a(float x) {  // 2^x, one v_exp_f32
  float r;
  asm("v_exp_f32 %0, %1" : "=v"(r) : "v"(x));
  return r;
}

// Dekker split of 8 fp32 into fp16 hi + fp16 lo via v_cvt_pkrtz (RTZ pack).
// hi = RTZ(a) -> residual a - hi is exact (same binade); lo = RTZ(residual).
static __device__ __forceinline__ void split8_f16(float4 p, float4 q,
                                                  f16x8& hi, f16x8& lo) {
  float a[8] = {p.x, p.y, p.z, p.w, q.x, q.y, q.z, q.w};
  union { h16x2 h2[4]; f16x8 v; } H, L;
#pragma unroll
  for (int i = 0; i < 4; ++i) {
    h16x2 h = __builtin_amdgcn_cvt_pkrtz(a[2 * i], a[2 * i + 1]);
    H.h2[i] = h;
    float r0 = a[2 * i] - (float)h.x;
    float r1 = a[2 * i + 1] - (float)h.y;
    L.h2[i] = __builtin_amdgcn_cvt_pkrtz(r0, r1);
  }
  hi = H.v;
  lo = L.v;
}

#define MAX3(a, b, c) fmaxf(fmaxf(a, b), c)

// byte address of (row, byteoff) in a row-stride-128B tile image, XOR-swizzled.
#define SWZ(row, byteoff) ((((row) * 128) + (byteoff)) ^ (((row) & 7) << 4))

// sigma: key -> storage col within a 64-block so PV fragment (ks,g) reads keys
// kappa(ks,g,j)=16(ks+2(j>>2))+4g+(j&3) as contiguous cols 32ks+8g+j.
static __device__ __forceinline__ int sigma64(int k) {
  return (k & 3) | (((k >> 5) & 1) << 2) | (((k >> 2) & 3) << 3) | (((k >> 4) & 1) << 5);
}

#define GLOAD16(gp, lp)                                              \
  __builtin_amdgcn_global_load_lds(                                  \
      (const __attribute__((address_space(1))) void*)(gp),           \
      (__attribute__((address_space(3))) void*)(lp), 16, 0, 0)

// ---------------- weight prep (fragment-packed, fp16 QKV weights) ----------------
__global__ __launch_bounds__(256) void prep_weights(const float* __restrict__ Wq,
                                                    const float* __restrict__ Wk,
                                                    const float* __restrict__ Wv,
                                                    const float* __restrict__ Wo,
                                                    u16* __restrict__ Wall,
                                                    u16* __restrict__ WoTp) {
  int i = blockIdx.x * 256 + threadIdx.x;
  if (i < 786432) {
    int which = i / 262144, rem = i - which * 262144;
    int b = rem >> 15, r2 = rem & 32767;
    int c = r2 >> 9, r = r2 & 511;
    const float* W = which == 0 ? Wq : which == 1 ? Wk : Wv;
    float x = W[(b << 15) + r * 64 + c];
    size_t off = (size_t)(which * 8 + b) * 32768 +
                 (size_t)((r >> 5) * 4 + (c >> 4)) * 512 +
                 ((((r & 31) >> 3) * 16) + (c & 15)) * 8 + (r & 7);
    Wall[off] = f2h(x);
  } else if (i < 786432 + 262144) {
    int rem = i - 786432;
    int c = rem >> 9, r = rem & 511;
    size_t off = (size_t)(c >> 6) * 32768 +
                 (size_t)((r >> 5) * 4 + ((c >> 4) & 3)) * 512 +
                 ((((r & 31) >> 3) * 16) + (c & 15)) * 8 + (r & 7);
    WoTp[off] = f2bf(Wo[r * 512 + c]);
  }
}

// ------------- fused projection GEMM (fp16, 32 rows/wave, 3-slot pipeline) -------------
__global__ __launch_bounds__(256) void proj_gemm(const float* __restrict__ Q,
                                                 const float* __restrict__ Kin,
                                                 const float* __restrict__ Vin,
                                                 const u16* __restrict__ Wall,
                                                 u16* __restrict__ qh,
                                                 u16* __restrict__ khg,
                                                 u16* __restrict__ vsg) {
  const int n = 4096, K = 512, N = 64;
  int rb = blockIdx.x;
  int which = blockIdx.y >> 3, b = blockIdx.y & 7;
  int wave = threadIdx.x >> 6, lane = threadIdx.x & 63;
  int lr = lane & 15, lg = lane >> 4;
  int row0 = rb * 128 + wave * 32;

  const float* A = which == 0 ? Q : which == 1 ? Kin : Vin;
  const u16* Bp = Wall + (size_t)(which * 8 + b) * 32768 + lane * 8;
  const float* Ar0 = A + (size_t)(row0 + lr) * K + lg * 8;
  const float* Ar1 = Ar0 + (size_t)16 * K;

  f32x4 acc[2][4] = {};

  float4 ax[3][4];
  f16x8 bw[3][4];
#pragma unroll
  for (int p = 0; p < 3; ++p) {
    ax[p][0] = *(const float4*)(Ar0 + p * 32);
    ax[p][1] = *(const float4*)(Ar0 + p * 32 + 4);
    ax[p][2] = *(const float4*)(Ar1 + p * 32);
    ax[p][3] = *(const float4*)(Ar1 + p * 32 + 4);
#pragma unroll
    for (int ct = 0; ct < 4; ++ct)
      bw[p][ct] = *(const f16x8*)(Bp + (p * 4 + ct) * 512);
  }

#pragma unroll
  for (int ks = 0; ks < 16; ++ks) {
    int s = ks % 3;
    f16x8 ah0, al0, ah1, al1;
    split8_f16(ax[s][0], ax[s][1], ah0, al0);
    split8_f16(ax[s][2], ax[s][3], ah1, al1);
    if (ks < 13) {
      ax[s][0] = *(const float4*)(Ar0 + (ks + 3) * 32);
      ax[s][1] = *(const float4*)(Ar0 + (ks + 3) * 32 + 4);
      ax[s][2] = *(const float4*)(Ar1 + (ks + 3) * 32);
      ax[s][3] = *(const float4*)(Ar1 + (ks + 3) * 32 + 4);
    }
#pragma unroll
    for (int ct = 0; ct < 4; ++ct) {
      acc[0][ct] = __builtin_amdgcn_mfma_f32_16x16x32_f16(ah0, bw[s][ct], acc[0][ct], 0, 0, 0);
      acc[0][ct] = __builtin_amdgcn_mfma_f32_16x16x32_f16(al0, bw[s][ct], acc[0][ct], 0, 0, 0);
      acc[1][ct] = __builtin_amdgcn_mfma_f32_16x16x32_f16(ah1, bw[s][ct], acc[1][ct], 0, 0, 0);
      acc[1][ct] = __builtin_amdgcn_mfma_f32_16x16x32_f16(al1, bw[s][ct], acc[1][ct], 0, 0, 0);
    }
    if (ks < 13) {
#pragma unroll
      for (int ct = 0; ct < 4; ++ct)
        bw[s][ct] = *(const f16x8*)(Bp + ((ks + 3) * 4 + ct) * 512);
    }
  }

  const float QSCALE = 0.125f * 1.44269504f;  // 1/sqrt(64) * log2(e)
#pragma unroll
  for (int b2 = 0; b2 < 2; ++b2)
#pragma unroll
    for (int ct = 0; ct < 4; ++ct)
#pragma unroll
      for (int r = 0; r < 4; ++r) {
        float v = acc[b2][ct][r];
        int row = row0 + b2 * 16 + lg * 4 + r;
        int col = ct * 16 + lr;
        if (which == 2) {
          size_t byte = ((size_t)b * 64 + (row >> 6)) * 8192 +
                        SWZ(col, 2 * sigma64(row & 63));
          *(u16*)((char*)vsg + byte) = f2bf(v);
        } else if (which == 1) {
          size_t byte = ((size_t)b * 64 + (row >> 6)) * 8192 + SWZ(row & 63, col * 2);
          *(u16*)((char*)khg + byte) = f2h(v);
        } else {
          qh[((size_t)b * n + row) * N + col] = f2h(v * QSCALE);
        }
      }
}

// ---------------- flash attention: 4 waves x 32 q-rows, split-KV x4 ----------------
// Bias-init softmax: QK accumulator starts at -m (per-lane q-row bias), so the
// common path applies exp2 with no subtraction. m0 = 0 (finite; -inf would
// absorb qk in f32). Rare path (mx_b > 8): re-bias s, rescale accO/accL.
__global__ __launch_bounds__(256, 4) void attn_kernel(const u16* __restrict__ qh,
                                                      const u16* __restrict__ khg,
                                                      const u16* __restrict__ vsg,
                                                      u16* __restrict__ Opart,
                                                      float2* __restrict__ ml) {
  const int n = 4096, d = 64;
  int bid = blockIdx.x;
  int j = bid & 7, w = bid >> 3;
  int grp = j * 4 + (w >> 5);  // = h*4 + part; all blocks of grp share bid%8
  int qb = w & 31;
  int h = grp >> 2, part = grp & 3;
  int wave = threadIdx.x >> 6, lane = threadIdx.x & 63;
  int c = lane & 15, g = lane >> 4;

  __shared__ char SB[32768];  // [KH0 8K][KH1 8K][VS0 8K][VS1 8K]

  int qrow0 = qb * 128 + wave * 32;
  f16x8 qf[2][2];
#pragma unroll
  for (int b2 = 0; b2 < 2; ++b2)
#pragma unroll
    for (int ks = 0; ks < 2; ++ks) {
      size_t qoff = ((size_t)h * n + qrow0 + b2 * 16 + c) * d + ks * 32 + g * 8;
      qf[b2][ks] = *(const f16x8*)(qh + qoff);
    }

  int koff[4][2];
#pragma unroll
  for (int ct = 0; ct < 4; ++ct)
#pragma unroll
    for (int ks = 0; ks < 2; ++ks)
      koff[ct][ks] = SWZ(ct * 16 + c, ks * 64 + g * 16);

  union { unsigned w[4]; bf16x8 v; } ones;
  ones.w[0] = 0x3f803f80u; ones.w[1] = 0x3f803f80u;
  ones.w[2] = 0x3f803f80u; ones.w[3] = 0x3f803f80u;

  f32x4 accO[2][4] = {};
  f32x4 accL[2] = {};
  float m[2] = {0.f, 0.f};          // running max, log2 units (finite init)
  f32x4 sinit[2] = {};              // broadcast of -m[b2] (accumulator C-init)

  const char* khB = (const char*)khg + ((size_t)h * 64 + part * 16) * 8192;
  const char* vsB = (const char*)vsg + ((size_t)h * 64 + part * 16) * 8192;
  int so = wave * 2048;
  int sg = so + lane * 16;

  const char* kgp = khB + sg;  // running per-lane source pointers (+8192/tile)
  const char* vgp = vsB + sg;

#define STAGE(BUF)                                                  \
  do {                                                              \
    char* kd_ = SB + (BUF)*8192 + so;                               \
    char* vd_ = SB + 16384 + (BUF)*8192 + so;                       \
    GLOAD16(kgp, kd_);                                              \
    GLOAD16(kgp + 1024, kd_ + 1024);                                \
    GLOAD16(vgp, vd_);                                              \
    GLOAD16(vgp + 1024, vd_ + 1024);                                \
    kgp += 8192;                                                    \
    vgp += 8192;                                                    \
  } while (0)

#define TILE(IT, CUR)                                                          \
  do {                                                                         \
    asm volatile("s_waitcnt vmcnt(0)" ::: "memory");                           \
    __builtin_amdgcn_s_barrier();                                              \
    asm volatile("" ::: "memory");                                             \
    if ((IT) < 15) STAGE(1 - (CUR));                                           \
    f32x4 s[2][4];                                                             \
    _Pragma("unroll") for (int b2 = 0; b2 < 2; ++b2)                           \
        _Pragma("unroll") for (int ct = 0; ct < 4; ++ct)                       \
            s[b2][ct] = sinit[b2];                                             \
    __builtin_amdgcn_s_setprio(1);                                             \
    _Pragma("unroll") for (int ct = 0; ct < 4; ++ct) {                         \
      _Pragma("unroll") for (int ks = 0; ks < 2; ++ks) {                       \
        f16x8 kf = *(const f16x8*)(SB + (CUR)*8192 + koff[ct][ks]);            \
        s[0][ct] = __builtin_amdgcn_mfma_f32_16x16x32_f16(kf, qf[0][ks],       \
                                                          s[0][ct], 0, 0, 0);  \
        s[1][ct] = __builtin_amdgcn_mfma_f32_16x16x32_f16(kf, qf[1][ks],       \
                                                          s[1][ct], 0, 0, 0);  \
      }                                                                        \
    }                                                                          \
    __builtin_amdgcn_s_setprio(0);                                             \
    float mxv[2];                                                              \
    _Pragma("unroll") for (int b2 = 0; b2 < 2; ++b2) {                         \
      float t0 = MAX3(s[b2][0][0], s[b2][0][1], s[b2][0][2]);                  \
      float t1 = MAX3(s[b2][0][3], s[b2][1][0], s[b2][1][1]);                  \
      float t2 = MAX3(s[b2][1][2], s[b2][1][3], s[b2][2][0]);                  \
      float t3 = MAX3(s[b2][2][1], s[b2][2][2], s[b2][2][3]);                  \
      float t4 = MAX3(s[b2][3][0], s[b2][3][1], s[b2][3][2]);                  \
      mxv[b2] = fmaxf(MAX3(t0, t1, t2), MAX3(t3, t4, s[b2][3][3]));            \
    }                                                                          \
    _Pragma("unroll") for (int b2 = 0; b2 < 2; ++b2)                           \
        mxv[b2] = fmaxf(mxv[b2], __shfl_xor(mxv[b2], 16));                     \
    _Pragma("unroll") for (int b2 = 0; b2 < 2; ++b2)                           \
        mxv[b2] = fmaxf(mxv[b2], __shfl_xor(mxv[b2], 32));                     \
    _Pragma("unroll") for (int b2 = 0; b2 < 2; ++b2) {                         \
      bool need = mxv[b2] > 8.0f; /* biased: mx - m_old > 8 */                 \
      if (__any(need)) {          /* rare re-bias + rescale path */            \
        float dl = need ? mxv[b2] : 0.f;                                       \
        float alpha = exp2a(-dl);                                              \
        m[b2] += dl;                                                           \
        _Pragma("unroll") for (int e = 0; e < 4; ++e) sinit[b2][e] -= dl;      \
        _Pragma("unroll") for (int ct = 0; ct < 4; ++ct)                       \
            _Pragma("unroll") for (int e = 0; e < 4; ++e)                      \
                s[b2][ct][e] -= dl;                                            \
        _Pragma("unroll") for (int r = 0; r < 4; ++r) {                        \
          float ar = __shfl(alpha, g * 4 + r);                                 \
          accL[b2][r] *= ar;                                                   \
          _Pragma("unroll") for (int dt = 0; dt < 4; ++dt)                     \
              accO[b2][dt][r] *= ar;                                           \
        }                                                                      \
      }                                                                        \
      _Pragma("unroll") for (int ct = 0; ct < 4; ++ct) {                       \
        s[b2][ct][0] = exp2a(s[b2][ct][0]);                                    \
        s[b2][ct][1] = exp2a(s[b2][ct][1]);                                    \
        s[b2][ct][2] = exp2a(s[b2][ct][2]);                                    \
        s[b2][ct][3] = exp2a(s[b2][ct][3]);                                    \
      }                                                                        \
    }                                                                          \
    union { unsigned w[4]; bf16x8 v; } pa[2][2];                               \
    _Pragma("unroll") for (int b2 = 0; b2 < 2; ++b2)                           \
        _Pragma("unroll") for (int ks = 0; ks < 2; ++ks) {                     \
      pa[b2][ks].w[0] = cvt_pk_bf16(s[b2][ks][0], s[b2][ks][1]);               \
      pa[b2][ks].w[1] = cvt_pk_bf16(s[b2][ks][2], s[b2][ks][3]);               \
      pa[b2][ks].w[2] = cvt_pk_bf16(s[b2][ks + 2][0], s[b2][ks + 2][1]);       \
      pa[b2][ks].w[3] = cvt_pk_bf16(s[b2][ks + 2][2], s[b2][ks + 2][3]);       \
    }                                                                          \
    __builtin_amdgcn_s_setprio(1);                                             \
    _Pragma("unroll") for (int dt = 0; dt < 4; ++dt) {                         \
      _Pragma("unroll") for (int ks = 0; ks < 2; ++ks) {                       \
        bf16x8 vf =                                                            \
            *(const bf16x8*)(SB + 16384 + (CUR)*8192 + koff[dt][ks]);          \
        accO[0][dt] = __builtin_amdgcn_mfma_f32_16x16x32_bf16(                 \
            pa[0][ks].v, vf, accO[0][dt], 0, 0, 0);                            \
        accO[1][dt] = __builtin_amdgcn_mfma_f32_16x16x32_bf16(                 \
            pa[1][ks].v, vf, accO[1][dt], 0, 0, 0);                            \
      }                                                                        \
    }                                                                          \
    accL[0] = __builtin_amdgcn_mfma_f32_16x16x32_bf16(pa[0][0].v, ones.v,      \
                                                      accL[0], 0, 0, 0);       \
    accL[0] = __builtin_amdgcn_mfma_f32_16x16x32_bf16(pa[0][1].v, ones.v,      \
                                                      accL[0], 0, 0, 0);       \
    accL[1] = __builtin_amdgcn_mfma_f32_16x16x32_bf16(pa[1][0].v, ones.v,      \
                                                      accL[1], 0, 0, 0);       \
    accL[1] = __builtin_amdgcn_mfma_f32_16x16x32_bf16(pa[1][1].v, ones.v,      \
                                                      accL[1], 0, 0, 0);       \
    __builtin_amdgcn_s_setprio(0);                                             \
  } while (0)

  STAGE(0);
#pragma unroll 1
  for (int it2 = 0; it2 < 8; ++it2) {
    TILE(it2 * 2, 0);
    TILE(it2 * 2 + 1, 1);
  }
#undef TILE
#undef STAGE

  // epilogue: unnormalized O + (m,l); m in log2 units
  u16* Ob = Opart + (((size_t)part * 8 + h) * n) * d;
  float2* mlp = ml + ((size_t)part * 8 + h) * n;
#pragma unroll
  for (int b2 = 0; b2 < 2; ++b2) {
#pragma unroll
    for (int r = 0; r < 4; ++r) {
      int row = qrow0 + b2 * 16 + g * 4 + r;
#pragma unroll
      for (int dt = 0; dt < 4; ++dt)
        Ob[(size_t)row * d + dt * 16 + c] = f2bf(accO[b2][dt][r]);
      float mrow = __shfl(m[b2], g * 4 + r);
      if (c == 0)
        mlp[qrow0 + b2 * 16 + g * 4 + r] = make_float2(mrow, accL[b2][r]);
    }
  }
}

// ---------------- combine the four KV parts (m in log2 units) ----------------
__global__ __launch_bounds__(256) void attn_combine(const u16* __restrict__ Opart,
                                                    const float2* __restrict__ ml,
                                                    u16* __restrict__ att) {
  int tid = blockIdx.x * 256 + threadIdx.x;
  int chunk = tid & 7;
  int h = (tid >> 3) & 7;
  int row = tid >> 6;
  float2 mls[4];
  float mstar = -INFINITY;
#pragma unroll
  for (int p = 0; p < 4; ++p) {
    mls[p] = ml[((size_t)p * 8 + h) * 4096 + row];
    mstar = fmaxf(mstar, mls[p].x);
  }
  float w[4], denom = 0.f;
#pragma unroll
  for (int p = 0; p < 4; ++p) {
    w[p] = exp2a(mls[p].x - mstar);
    denom += mls[p].y * w[p];
  }
  float inv = 1.f / denom;
  float res[8] = {};
#pragma unroll
  for (int p = 0; p < 4; ++p) {
    bf16x8 o = *(const bf16x8*)(Opart + (((size_t)p * 8 + h) * 4096 + row) * 64 + chunk * 8);
    float wp = w[p] * inv;
#pragma unroll
    for (int jj = 0; jj < 8; ++jj) res[jj] += bf2f((u16)o[jj]) * wp;
  }
  bf16x8 rv;
#pragma unroll
  for (int jj = 0; jj < 8; ++jj) rv[jj] = (short)f2bf(res[jj]);
  *(bf16x8*)(att + (size_t)row * 512 + h * 64 + chunk * 8) = rv;
}

// ------- final projection: out = att @ Wo (fp32 out), 4-slot prefetch -------
__global__ __launch_bounds__(256) void final_gemm(const u16* __restrict__ A,
                                                  const u16* __restrict__ BTp,
                                                  float* __restrict__ out,
                                                  int M, int K, int N) {
  int rb = blockIdx.x, cb = blockIdx.y;
  int wave = threadIdx.x >> 6, lane = threadIdx.x & 63;
  int lr = lane & 15, lg = lane >> 4;
  int row0 = rb * 64 + wave * 16;

  const u16* Arow = A + (size_t)(row0 + lr) * K + lg * 8;
  const u16* Bp = BTp + (size_t)cb * 32768 + lane * 8;

  f32x4 acc[4] = {};
  bf16x8 a[4];
  bf16x8 bb[4][4];
#pragma unroll
  for (int p = 0; p < 4; ++p) {
    a[p] = *(const bf16x8*)(Arow + p * 32);
#pragma unroll
    for (int ct = 0; ct < 4; ++ct)
      bb[p][ct] = *(const bf16x8*)(Bp + (p * 4 + ct) * 512);
  }

#pragma unroll
  for (int ks = 0; ks < 16; ++ks) {
    int s = ks & 3;
#pragma unroll
    for (int ct = 0; ct < 4; ++ct)
      acc[ct] = __builtin_amdgcn_mfma_f32_16x16x32_bf16(a[s], bb[s][ct], acc[ct], 0, 0, 0);
    if (ks < 12) {
      a[s] = *(const bf16x8*)(Arow + (ks + 4) * 32);
#pragma unroll
      for (int ct = 0; ct < 4; ++ct)
        bb[s][ct] = *(const bf16x8*)(Bp + ((ks + 4) * 4 + ct) * 512);
    }
  }
#pragma unroll
  for (int ct = 0; ct < 4; ++ct)
#pragma unroll
    for (int r = 0; r < 4; ++r)
      out[(size_t)(row0 + lg * 4 + r) * N + cb * 64 + ct * 16 + lr] = acc[ct][r];
}

// ---------------- launch ----------------
extern "C" void kernel_launch(void* const* d_in, const int* in_sizes, int n_in,
                              void* d_out, int out_size, void* d_ws, size_t ws_size,
                              hipStream_t stream) {
  const float* Q = (const float*)d_in[0];
  const float* K = (const float*)d_in[1];
  const float* V = (const float*)d_in[2];
  const float* Wq = (const float*)d_in[3];
  const float* Wk = (const float*)d_in[4];
  const float* Wv = (const float*)d_in[5];
  const float* Wo = (const float*)d_in[6];
  float* out = (float*)d_out;

  const int n = 4096, dim = 512;
  const size_t KB = 1 << 10, MB = 1 << 20;
  char* ws = (char*)d_ws;
  u16* qh     = (u16*)(ws + 0 * MB);   // 4 MB, fp16 (pre-scaled log2e/8)
  u16* khg    = (u16*)(ws + 4 * MB);   // 4 MB, fp16 swizzled images
  u16* vsg    = (u16*)(ws + 8 * MB);   // 4 MB, bf16 swizzled sigma-permuted
  u16* Opart  = (u16*)(ws + 12 * MB);  // 16 MB (4 parts) -> ends 28 MB
  u16* Wall   = (u16*)(ws + 12 * MB);  // 1.5 MB fp16, inside Opart (dead by attn)
  float2* ml  = (float2*)(ws + 28 * MB);          // 1 MB
  u16* WoTp   = (u16*)(ws + 29 * MB);             // 512 KB -> peak 29.5 MB
  u16* att    = khg;  // khg dead after attn; combine writes att here

  prep_weights<<<4096, 256, 0, stream>>>(Wq, Wk, Wv, Wo, Wall, WoTp);

  proj_gemm<<<dim3(32, 24), 256, 0, stream>>>(Q, K, V, Wall, qh, khg, vsg);

  attn_kernel<<<1024, 256, 0, stream>>>(qh, khg, vsg, Opart, ml);
  attn_combine<<<(n * 8 * 8) / 256, 256, 0, stream>>>(Opart, ml, att);

  final_gemm<<<dim3(n / 64, dim / 64), 256, 0, stream>>>(att, WoTp, out, n, dim, dim);
}

// Round 16
// 102.586 us; speedup vs baseline: 1.0438x; 1.0438x over previous
//
#include <hip/hip_runtime.h>

// MultiHeadAttentionLayer: n=4096, dim=512, h=8, d=64, fp32 in/out.
// R15: attn fully reverted to R13's measured-good internals (R14's bias-init
// added ~15MB of memory traffic and regressed). Kept from R14: proj RTZ-pack
// Dekker split. New: prep_weights index mapping swapped so reads are
// coalesced (consecutive threads walk the weight column, not the 256B-strided
// row) -- was ~16x line overfetch.

typedef __attribute__((ext_vector_type(8))) short bf16x8;
typedef __attribute__((ext_vector_type(8))) _Float16 f16x8;
typedef __attribute__((ext_vector_type(2))) __fp16 h16x2;
typedef __attribute__((ext_vector_type(4))) float f32x4;
typedef unsigned short u16;

static __device__ __forceinline__ u16 f2bf(float f) {
  union { float f; unsigned u; } v; v.f = f;
  unsigned r = v.u + 0x7fffu + ((v.u >> 16) & 1u);
  return (u16)(r >> 16);
}
static __device__ __forceinline__ float bf2f(u16 h) {
  union { unsigned u; float f; } v; v.u = ((unsigned)h) << 16; return v.f;
}
static __device__ __forceinline__ u16 f2h(float f) {
  union { _Float16 h; u16 u; } v; v.h = (_Float16)f; return v.u;
}
static __device__ __forceinline__ unsigned cvt_pk_bf16(float lo, float hi) {
  unsigned r;
  asm("v_cvt_pk_bf16_f32 %0, %1, %2" : "=v"(r) : "v"(lo), "v"(hi));
  return r;
}
static __device__ __forceinline__ float exp2a(float x) {  // 2^x, one v_exp_f32
  float r;
  asm("v_exp_f32 %0, %1" : "=v"(r) : "v"(x));
  return r;
}

// Dekker split of 8 fp32 into fp16 hi + fp16 lo via v_cvt_pkrtz (RTZ pack).
// hi = RTZ(a) -> residual a - hi is exact (same binade); lo = RTZ(residual).
static __device__ __forceinline__ void split8_f16(float4 p, float4 q,
                                                  f16x8& hi, f16x8& lo) {
  float a[8] = {p.x, p.y, p.z, p.w, q.x, q.y, q.z, q.w};
  union { h16x2 h2[4]; f16x8 v; } H, L;
#pragma unroll
  for (int i = 0; i < 4; ++i) {
    h16x2 h = __builtin_amdgcn_cvt_pkrtz(a[2 * i], a[2 * i + 1]);
    H.h2[i] = h;
    float r0 = a[2 * i] - (float)h.x;
    float r1 = a[2 * i + 1] - (float)h.y;
    L.h2[i] = __builtin_amdgcn_cvt_pkrtz(r0, r1);
  }
  hi = H.v;
  lo = L.v;
}

#define MAX3(a, b, c) fmaxf(fmaxf(a, b), c)

// byte address of (row, byteoff) in a row-stride-128B tile image, XOR-swizzled.
#define SWZ(row, byteoff) ((((row) * 128) + (byteoff)) ^ (((row) & 7) << 4))

// sigma: key -> storage col within a 64-block so PV fragment (ks,g) reads keys
// kappa(ks,g,j)=16(ks+2(j>>2))+4g+(j&3) as contiguous cols 32ks+8g+j.
static __device__ __forceinline__ int sigma64(int k) {
  return (k & 3) | (((k >> 5) & 1) << 2) | (((k >> 2) & 3) << 3) | (((k >> 4) & 1) << 5);
}

#define GLOAD16(gp, lp)                                              \
  __builtin_amdgcn_global_load_lds(                                  \
      (const __attribute__((address_space(1))) void*)(gp),           \
      (__attribute__((address_space(3))) void*)(lp), 16, 0, 0)

// ---------------- weight prep (fragment-packed, COALESCED reads) ----------------
// QKV: i = ((which*8+b)*512 + r)*64 + c  -> consecutive threads walk c ->
// reads W[r*64+c] contiguous. Wo: rem = r*512 + c -> reads contiguous.
__global__ __launch_bounds__(256) void prep_weights(const float* __restrict__ Wq,
                                                    const float* __restrict__ Wk,
                                                    const float* __restrict__ Wv,
                                                    const float* __restrict__ Wo,
                                                    u16* __restrict__ Wall,
                                                    u16* __restrict__ WoTp) {
  int i = blockIdx.x * 256 + threadIdx.x;
  if (i < 786432) {
    int c = i & 63;
    int r = (i >> 6) & 511;
    int panel = i >> 15;  // which*8 + b
    int which = panel >> 3, b = panel & 7;
    const float* W = which == 0 ? Wq : which == 1 ? Wk : Wv;
    float x = W[(b << 15) + r * 64 + c];
    size_t off = (size_t)panel * 32768 +
                 (size_t)((r >> 5) * 4 + (c >> 4)) * 512 +
                 ((((r & 31) >> 3) * 16) + (c & 15)) * 8 + (r & 7);
    Wall[off] = f2h(x);
  } else if (i < 786432 + 262144) {
    int rem = i - 786432;
    int c = rem & 511;
    int r = rem >> 9;
    float x = Wo[r * 512 + c];
    size_t off = (size_t)(c >> 6) * 32768 +
                 (size_t)((r >> 5) * 4 + ((c >> 4) & 3)) * 512 +
                 ((((r & 31) >> 3) * 16) + (c & 15)) * 8 + (r & 7);
    WoTp[off] = f2bf(x);
  }
}

// ------------- fused projection GEMM (fp16, 32 rows/wave, 3-slot pipeline) -------------
__global__ __launch_bounds__(256) void proj_gemm(const float* __restrict__ Q,
                                                 const float* __restrict__ Kin,
                                                 const float* __restrict__ Vin,
                                                 const u16* __restrict__ Wall,
                                                 u16* __restrict__ qh,
                                                 u16* __restrict__ khg,
                                                 u16* __restrict__ vsg) {
  const int n = 4096, K = 512, N = 64;
  int rb = blockIdx.x;
  int which = blockIdx.y >> 3, b = blockIdx.y & 7;
  int wave = threadIdx.x >> 6, lane = threadIdx.x & 63;
  int lr = lane & 15, lg = lane >> 4;
  int row0 = rb * 128 + wave * 32;

  const float* A = which == 0 ? Q : which == 1 ? Kin : Vin;
  const u16* Bp = Wall + (size_t)(which * 8 + b) * 32768 + lane * 8;
  const float* Ar0 = A + (size_t)(row0 + lr) * K + lg * 8;
  const float* Ar1 = Ar0 + (size_t)16 * K;

  f32x4 acc[2][4] = {};

  float4 ax[3][4];
  f16x8 bw[3][4];
#pragma unroll
  for (int p = 0; p < 3; ++p) {
    ax[p][0] = *(const float4*)(Ar0 + p * 32);
    ax[p][1] = *(const float4*)(Ar0 + p * 32 + 4);
    ax[p][2] = *(const float4*)(Ar1 + p * 32);
    ax[p][3] = *(const float4*)(Ar1 + p * 32 + 4);
#pragma unroll
    for (int ct = 0; ct < 4; ++ct)
      bw[p][ct] = *(const f16x8*)(Bp + (p * 4 + ct) * 512);
  }

#pragma unroll
  for (int ks = 0; ks < 16; ++ks) {
    int s = ks % 3;
    f16x8 ah0, al0, ah1, al1;
    split8_f16(ax[s][0], ax[s][1], ah0, al0);
    split8_f16(ax[s][2], ax[s][3], ah1, al1);
    if (ks < 13) {
      ax[s][0] = *(const float4*)(Ar0 + (ks + 3) * 32);
      ax[s][1] = *(const float4*)(Ar0 + (ks + 3) * 32 + 4);
      ax[s][2] = *(const float4*)(Ar1 + (ks + 3) * 32);
      ax[s][3] = *(const float4*)(Ar1 + (ks + 3) * 32 + 4);
    }
#pragma unroll
    for (int ct = 0; ct < 4; ++ct) {
      acc[0][ct] = __builtin_amdgcn_mfma_f32_16x16x32_f16(ah0, bw[s][ct], acc[0][ct], 0, 0, 0);
      acc[0][ct] = __builtin_amdgcn_mfma_f32_16x16x32_f16(al0, bw[s][ct], acc[0][ct], 0, 0, 0);
      acc[1][ct] = __builtin_amdgcn_mfma_f32_16x16x32_f16(ah1, bw[s][ct], acc[1][ct], 0, 0, 0);
      acc[1][ct] = __builtin_amdgcn_mfma_f32_16x16x32_f16(al1, bw[s][ct], acc[1][ct], 0, 0, 0);
    }
    if (ks < 13) {
#pragma unroll
      for (int ct = 0; ct < 4; ++ct)
        bw[s][ct] = *(const f16x8*)(Bp + ((ks + 3) * 4 + ct) * 512);
    }
  }

  const float QSCALE = 0.125f * 1.44269504f;  // 1/sqrt(64) * log2(e)
#pragma unroll
  for (int b2 = 0; b2 < 2; ++b2)
#pragma unroll
    for (int ct = 0; ct < 4; ++ct)
#pragma unroll
      for (int r = 0; r < 4; ++r) {
        float v = acc[b2][ct][r];
        int row = row0 + b2 * 16 + lg * 4 + r;
        int col = ct * 16 + lr;
        if (which == 2) {
          size_t byte = ((size_t)b * 64 + (row >> 6)) * 8192 +
                        SWZ(col, 2 * sigma64(row & 63));
          *(u16*)((char*)vsg + byte) = f2bf(v);
        } else if (which == 1) {
          size_t byte = ((size_t)b * 64 + (row >> 6)) * 8192 + SWZ(row & 63, col * 2);
          *(u16*)((char*)khg + byte) = f2h(v);
        } else {
          qh[((size_t)b * n + row) * N + col] = f2h(v * QSCALE);
        }
      }
}

// ---------------- flash attention: 4 waves x 32 q-rows, split-KV x4 ----------------
// (R13 internals restored) 32KB double buffer, one barrier/tile, m in log2
// units, l via MFMA ones-column, defer-rescale threshold 8.
__global__ __launch_bounds__(256, 4) void attn_kernel(const u16* __restrict__ qh,
                                                      const u16* __restrict__ khg,
                                                      const u16* __restrict__ vsg,
                                                      u16* __restrict__ Opart,
                                                      float2* __restrict__ ml) {
  const int n = 4096, d = 64;
  int bid = blockIdx.x;
  int j = bid & 7, w = bid >> 3;
  int grp = j * 4 + (w >> 5);  // = h*4 + part; all blocks of grp share bid%8
  int qb = w & 31;
  int h = grp >> 2, part = grp & 3;
  int wave = threadIdx.x >> 6, lane = threadIdx.x & 63;
  int c = lane & 15, g = lane >> 4;

  __shared__ char SB[32768];  // [KH0 8K][KH1 8K][VS0 8K][VS1 8K]

  int qrow0 = qb * 128 + wave * 32;
  f16x8 qf[2][2];
#pragma unroll
  for (int b2 = 0; b2 < 2; ++b2)
#pragma unroll
    for (int ks = 0; ks < 2; ++ks) {
      size_t qoff = ((size_t)h * n + qrow0 + b2 * 16 + c) * d + ks * 32 + g * 8;
      qf[b2][ks] = *(const f16x8*)(qh + qoff);
    }

  int koff[4][2];
#pragma unroll
  for (int ct = 0; ct < 4; ++ct)
#pragma unroll
    for (int ks = 0; ks < 2; ++ks)
      koff[ct][ks] = SWZ(ct * 16 + c, ks * 64 + g * 16);

  union { unsigned w[4]; bf16x8 v; } ones;
  ones.w[0] = 0x3f803f80u; ones.w[1] = 0x3f803f80u;
  ones.w[2] = 0x3f803f80u; ones.w[3] = 0x3f803f80u;

  f32x4 accO[2][4] = {};
  f32x4 accL[2] = {};
  float m[2] = {-INFINITY, -INFINITY};

  const char* khB = (const char*)khg + ((size_t)h * 64 + part * 16) * 8192;
  const char* vsB = (const char*)vsg + ((size_t)h * 64 + part * 16) * 8192;
  int so = wave * 2048;
  int sg = so + lane * 16;

#define STAGE(tile, BUF)                                            \
  do {                                                              \
    const char* kg_ = khB + (size_t)(tile) * 8192 + sg;             \
    const char* vg_ = vsB + (size_t)(tile) * 8192 + sg;             \
    char* kd_ = SB + (BUF)*8192 + so;                               \
    char* vd_ = SB + 16384 + (BUF)*8192 + so;                       \
    GLOAD16(kg_, kd_);                                              \
    GLOAD16(kg_ + 1024, kd_ + 1024);                                \
    GLOAD16(vg_, vd_);                                              \
    GLOAD16(vg_ + 1024, vd_ + 1024);                                \
  } while (0)

#define TILE(IT, CUR)                                                          \
  do {                                                                         \
    asm volatile("s_waitcnt vmcnt(0)" ::: "memory");                           \
    __builtin_amdgcn_s_barrier();                                              \
    asm volatile("" ::: "memory");                                             \
    if ((IT) < 15) STAGE((IT) + 1, 1 - (CUR));                                 \
    f32x4 s[2][4] = {};                                                        \
    __builtin_amdgcn_s_setprio(1);                                             \
    _Pragma("unroll") for (int ct = 0; ct < 4; ++ct) {                         \
      _Pragma("unroll") for (int ks = 0; ks < 2; ++ks) {                       \
        f16x8 kf = *(const f16x8*)(SB + (CUR)*8192 + koff[ct][ks]);            \
        s[0][ct] = __builtin_amdgcn_mfma_f32_16x16x32_f16(kf, qf[0][ks],       \
                                                          s[0][ct], 0, 0, 0);  \
        s[1][ct] = __builtin_amdgcn_mfma_f32_16x16x32_f16(kf, qf[1][ks],       \
                                                          s[1][ct], 0, 0, 0);  \
      }                                                                        \
    }                                                                          \
    __builtin_amdgcn_s_setprio(0);                                             \
    float mxv[2];                                                              \
    _Pragma("unroll") for (int b2 = 0; b2 < 2; ++b2) {                         \
      float t0 = MAX3(s[b2][0][0], s[b2][0][1], s[b2][0][2]);                  \
      float t1 = MAX3(s[b2][0][3], s[b2][1][0], s[b2][1][1]);                  \
      float t2 = MAX3(s[b2][1][2], s[b2][1][3], s[b2][2][0]);                  \
      float t3 = MAX3(s[b2][2][1], s[b2][2][2], s[b2][2][3]);                  \
      float t4 = MAX3(s[b2][3][0], s[b2][3][1], s[b2][3][2]);                  \
      mxv[b2] = fmaxf(MAX3(t0, t1, t2), MAX3(t3, t4, s[b2][3][3]));            \
    }                                                                          \
    _Pragma("unroll") for (int b2 = 0; b2 < 2; ++b2)                           \
        mxv[b2] = fmaxf(mxv[b2], __shfl_xor(mxv[b2], 16));                     \
    _Pragma("unroll") for (int b2 = 0; b2 < 2; ++b2)                           \
        mxv[b2] = fmaxf(mxv[b2], __shfl_xor(mxv[b2], 32));                     \
    _Pragma("unroll") for (int b2 = 0; b2 < 2; ++b2) {                         \
      bool need = mxv[b2] > m[b2] + 8.0f; /* defer-rescale threshold */        \
      float mn = need ? mxv[b2] : m[b2];                                       \
      _Pragma("unroll") for (int ct = 0; ct < 4; ++ct) {                       \
        s[b2][ct][0] = exp2a(s[b2][ct][0] - mn);                               \
        s[b2][ct][1] = exp2a(s[b2][ct][1] - mn);                               \
        s[b2][ct][2] = exp2a(s[b2][ct][2] - mn);                               \
        s[b2][ct][3] = exp2a(s[b2][ct][3] - mn);                               \
      }                                                                        \
      if (__any(need)) {                                                       \
        float alpha = exp2a(m[b2] - mn);                                       \
        m[b2] = mn;                                                            \
        _Pragma("unroll") for (int r = 0; r < 4; ++r) {                        \
          float ar = __shfl(alpha, g * 4 + r);                                 \
          accL[b2][r] *= ar;                                                   \
          _Pragma("unroll") for (int dt = 0; dt < 4; ++dt)                     \
              accO[b2][dt][r] *= ar;                                           \
        }                                                                      \
      }                                                                        \
    }                                                                          \
    union { unsigned w[4]; bf16x8 v; } pa[2][2];                               \
    _Pragma("unroll") for (int b2 = 0; b2 < 2; ++b2)                           \
        _Pragma("unroll") for (int ks = 0; ks < 2; ++ks) {                     \
      pa[b2][ks].w[0] = cvt_pk_bf16(s[b2][ks][0], s[b2][ks][1]);               \
      pa[b2][ks].w[1] = cvt_pk_bf16(s[b2][ks][2], s[b2][ks][3]);               \
      pa[b2][ks].w[2] = cvt_pk_bf16(s[b2][ks + 2][0], s[b2][ks + 2][1]);       \
      pa[b2][ks].w[3] = cvt_pk_bf16(s[b2][ks + 2][2], s[b2][ks + 2][3]);       \
    }                                                                          \
    __builtin_amdgcn_s_setprio(1);                                             \
    _Pragma("unroll") for (int dt = 0; dt < 4; ++dt) {                         \
      _Pragma("unroll") for (int ks = 0; ks < 2; ++ks) {                       \
        bf16x8 vf =                                                            \
            *(const bf16x8*)(SB + 16384 + (CUR)*8192 + koff[dt][ks]);          \
        accO[0][dt] = __builtin_amdgcn_mfma_f32_16x16x32_bf16(                 \
            pa[0][ks].v, vf, accO[0][dt], 0, 0, 0);                            \
        accO[1][dt] = __builtin_amdgcn_mfma_f32_16x16x32_bf16(                 \
            pa[1][ks].v, vf, accO[1][dt], 0, 0, 0);                            \
      }                                                                        \
    }                                                                          \
    accL[0] = __builtin_amdgcn_mfma_f32_16x16x32_bf16(pa[0][0].v, ones.v,      \
                                                      accL[0], 0, 0, 0);       \
    accL[0] = __builtin_amdgcn_mfma_f32_16x16x32_bf16(pa[0][1].v, ones.v,      \
                                                      accL[0], 0, 0, 0);       \
    accL[1] = __builtin_amdgcn_mfma_f32_16x16x32_bf16(pa[1][0].v, ones.v,      \
                                                      accL[1], 0, 0, 0);       \
    accL[1] = __builtin_amdgcn_mfma_f32_16x16x32_bf16(pa[1][1].v, ones.v,      \
                                                      accL[1], 0, 0, 0);       \
    __builtin_amdgcn_s_setprio(0);                                             \
  } while (0)

  STAGE(0, 0);
#pragma unroll 1
  for (int it2 = 0; it2 < 8; ++it2) {
    TILE(it2 * 2, 0);
    TILE(it2 * 2 + 1, 1);
  }
#undef TILE
#undef STAGE

  // epilogue: unnormalized O + (m,l); m in log2 units.
  u16* Ob = Opart + (((size_t)part * 8 + h) * n) * d;
  float2* mlp = ml + ((size_t)part * 8 + h) * n;
#pragma unroll
  for (int b2 = 0; b2 < 2; ++b2) {
#pragma unroll
    for (int r = 0; r < 4; ++r) {
      int row = qrow0 + b2 * 16 + g * 4 + r;
#pragma unroll
      for (int dt = 0; dt < 4; ++dt)
        Ob[(size_t)row * d + dt * 16 + c] = f2bf(accO[b2][dt][r]);
      float mrow = __shfl(m[b2], g * 4 + r);
      if (c == 0)
        mlp[qrow0 + b2 * 16 + g * 4 + r] = make_float2(mrow, accL[b2][r]);
    }
  }
}

// ---------------- combine the four KV parts (m in log2 units) ----------------
__global__ __launch_bounds__(256) void attn_combine(const u16* __restrict__ Opart,
                                                    const float2* __restrict__ ml,
                                                    u16* __restrict__ att) {
  int tid = blockIdx.x * 256 + threadIdx.x;
  int chunk = tid & 7;
  int h = (tid >> 3) & 7;
  int row = tid >> 6;
  float2 mls[4];
  float mstar = -INFINITY;
#pragma unroll
  for (int p = 0; p < 4; ++p) {
    mls[p] = ml[((size_t)p * 8 + h) * 4096 + row];
    mstar = fmaxf(mstar, mls[p].x);
  }
  float w[4], denom = 0.f;
#pragma unroll
  for (int p = 0; p < 4; ++p) {
    w[p] = exp2a(mls[p].x - mstar);
    denom += mls[p].y * w[p];
  }
  float inv = 1.f / denom;
  float res[8] = {};
#pragma unroll
  for (int p = 0; p < 4; ++p) {
    bf16x8 o = *(const bf16x8*)(Opart + (((size_t)p * 8 + h) * 4096 + row) * 64 + chunk * 8);
    float wp = w[p] * inv;
#pragma unroll
    for (int jj = 0; jj < 8; ++jj) res[jj] += bf2f((u16)o[jj]) * wp;
  }
  bf16x8 rv;
#pragma unroll
  for (int jj = 0; jj < 8; ++jj) rv[jj] = (short)f2bf(res[jj]);
  *(bf16x8*)(att + (size_t)row * 512 + h * 64 + chunk * 8) = rv;
}

// ------- final projection: out = att @ Wo (fp32 out), 4-slot prefetch -------
__global__ __launch_bounds__(256) void final_gemm(const u16* __restrict__ A,
                                                  const u16* __restrict__ BTp,
                                                  float* __restrict__ out,
                                                  int M, int K, int N) {
  int rb = blockIdx.x, cb = blockIdx.y;
  int wave = threadIdx.x >> 6, lane = threadIdx.x & 63;
  int lr = lane & 15, lg = lane >> 4;
  int row0 = rb * 64 + wave * 16;

  const u16* Arow = A + (size_t)(row0 + lr) * K + lg * 8;
  const u16* Bp = BTp + (size_t)cb * 32768 + lane * 8;

  f32x4 acc[4] = {};
  bf16x8 a[4];
  bf16x8 bb[4][4];
#pragma unroll
  for (int p = 0; p < 4; ++p) {
    a[p] = *(const bf16x8*)(Arow + p * 32);
#pragma unroll
    for (int ct = 0; ct < 4; ++ct)
      bb[p][ct] = *(const bf16x8*)(Bp + (p * 4 + ct) * 512);
  }

#pragma unroll
  for (int ks = 0; ks < 16; ++ks) {
    int s = ks & 3;
#pragma unroll
    for (int ct = 0; ct < 4; ++ct)
      acc[ct] = __builtin_amdgcn_mfma_f32_16x16x32_bf16(a[s], bb[s][ct], acc[ct], 0, 0, 0);
    if (ks < 12) {
      a[s] = *(const bf16x8*)(Arow + (ks + 4) * 32);
#pragma unroll
      for (int ct = 0; ct < 4; ++ct)
        bb[s][ct] = *(const bf16x8*)(Bp + ((ks + 4) * 4 + ct) * 512);
    }
  }
#pragma unroll
  for (int ct = 0; ct < 4; ++ct)
#pragma unroll
    for (int r = 0; r < 4; ++r)
      out[(size_t)(row0 + lg * 4 + r) * N + cb * 64 + ct * 16 + lr] = acc[ct][r];
}

// ---------------- launch ----------------
extern "C" void kernel_launch(void* const* d_in, const int* in_sizes, int n_in,
                              void* d_out, int out_size, void* d_ws, size_t ws_size,
                              hipStream_t stream) {
  const float* Q = (const float*)d_in[0];
  const float* K = (const float*)d_in[1];
  const float* V = (const float*)d_in[2];
  const float* Wq = (const float*)d_in[3];
  const float* Wk = (const float*)d_in[4];
  const float* Wv = (const float*)d_in[5];
  const float* Wo = (const float*)d_in[6];
  float* out = (float*)d_out;

  const int n = 4096, dim = 512;
  const size_t KB = 1 << 10, MB = 1 << 20;
  char* ws = (char*)d_ws;
  u16* qh     = (u16*)(ws + 0 * MB);   // 4 MB, fp16 (pre-scaled log2e/8)
  u16* khg    = (u16*)(ws + 4 * MB);   // 4 MB, fp16 swizzled images
  u16* vsg    = (u16*)(ws + 8 * MB);   // 4 MB, bf16 swizzled sigma-permuted
  u16* Opart  = (u16*)(ws + 12 * MB);  // 16 MB (4 parts) -> ends 28 MB
  u16* Wall   = (u16*)(ws + 12 * MB);  // 1.5 MB fp16, inside Opart (dead by attn)
  float2* ml  = (float2*)(ws + 28 * MB);          // 1 MB
  u16* WoTp   = (u16*)(ws + 29 * MB);             // 512 KB -> peak 29.5 MB
  u16* att    = khg;  // khg dead after attn; combine writes att here

  prep_weights<<<4096, 256, 0, stream>>>(Wq, Wk, Wv, Wo, Wall, WoTp);

  proj_gemm<<<dim3(32, 24), 256, 0, stream>>>(Q, K, V, Wall, qh, khg, vsg);

  attn_kernel<<<1024, 256, 0, stream>>>(qh, khg, vsg, Opart, ml);
  attn_combine<<<(n * 8 * 8) / 256, 256, 0, stream>>>(Opart, ml, att);

  final_gemm<<<dim3(n / 64, dim / 64), 256, 0, stream>>>(att, WoTp, out, n, dim, dim);
}

// Round 17
// 102.490 us; speedup vs baseline: 1.0447x; 1.0009x over previous
//
#include <hip/hip_runtime.h>

// MultiHeadAttentionLayer: n=4096, dim=512, h=8, d=64, fp32 in/out.
// R15: attn fully reverted to R13's measured-good internals (R14's bias-init
// added ~15MB of memory traffic and regressed). Kept from R14: proj RTZ-pack
// Dekker split. New: prep_weights index mapping swapped so reads are
// coalesced (consecutive threads walk the weight column, not the 256B-strided
// row) -- was ~16x line overfetch.

typedef __attribute__((ext_vector_type(8))) short bf16x8;
typedef __attribute__((ext_vector_type(8))) _Float16 f16x8;
typedef __attribute__((ext_vector_type(2))) __fp16 h16x2;
typedef __attribute__((ext_vector_type(4))) float f32x4;
typedef unsigned short u16;

static __device__ __forceinline__ u16 f2bf(float f) {
  union { float f; unsigned u; } v; v.f = f;
  unsigned r = v.u + 0x7fffu + ((v.u >> 16) & 1u);
  return (u16)(r >> 16);
}
static __device__ __forceinline__ float bf2f(u16 h) {
  union { unsigned u; float f; } v; v.u = ((unsigned)h) << 16; return v.f;
}
static __device__ __forceinline__ u16 f2h(float f) {
  union { _Float16 h; u16 u; } v; v.h = (_Float16)f; return v.u;
}
static __device__ __forceinline__ unsigned cvt_pk_bf16(float lo, float hi) {
  unsigned r;
  asm("v_cvt_pk_bf16_f32 %0, %1, %2" : "=v"(r) : "v"(lo), "v"(hi));
  return r;
}
static __device__ __forceinline__ float exp2a(float x) {  // 2^x, one v_exp_f32
  float r;
  asm("v_exp_f32 %0, %1" : "=v"(r) : "v"(x));
  return r;
}

// Dekker split of 8 fp32 into fp16 hi + fp16 lo via v_cvt_pkrtz (RTZ pack).
// hi = RTZ(a) -> residual a - hi is exact (same binade); lo = RTZ(residual).
static __device__ __forceinline__ void split8_f16(float4 p, float4 q,
                                                  f16x8& hi, f16x8& lo) {
  float a[8] = {p.x, p.y, p.z, p.w, q.x, q.y, q.z, q.w};
  union { h16x2 h2[4]; f16x8 v; } H, L;
#pragma unroll
  for (int i = 0; i < 4; ++i) {
    h16x2 h = __builtin_amdgcn_cvt_pkrtz(a[2 * i], a[2 * i + 1]);
    H.h2[i] = h;
    float r0 = a[2 * i] - (float)h.x;
    float r1 = a[2 * i + 1] - (float)h.y;
    L.h2[i] = __builtin_amdgcn_cvt_pkrtz(r0, r1);
  }
  hi = H.v;
  lo = L.v;
}

#define MAX3(a, b, c) fmaxf(fmaxf(a, b), c)

// byte address of (row, byteoff) in a row-stride-128B tile image, XOR-swizzled.
#define SWZ(row, byteoff) ((((row) * 128) + (byteoff)) ^ (((row) & 7) << 4))

// sigma: key -> storage col within a 64-block so PV fragment (ks,g) reads keys
// kappa(ks,g,j)=16(ks+2(j>>2))+4g+(j&3) as contiguous cols 32ks+8g+j.
static __device__ __forceinline__ int sigma64(int k) {
  return (k & 3) | (((k >> 5) & 1) << 2) | (((k >> 2) & 3) << 3) | (((k >> 4) & 1) << 5);
}

#define GLOAD16(gp, lp)                                              \
  __builtin_amdgcn_global_load_lds(                                  \
      (const __attribute__((address_space(1))) void*)(gp),           \
      (__attribute__((address_space(3))) void*)(lp), 16, 0, 0)

// ---------------- weight prep (fragment-packed, COALESCED reads) ----------------
// QKV: i = ((which*8+b)*512 + r)*64 + c  -> consecutive threads walk c ->
// reads W[r*64+c] contiguous. Wo: rem = r*512 + c -> reads contiguous.
__global__ __launch_bounds__(256) void prep_weights(const float* __restrict__ Wq,
                                                    const float* __restrict__ Wk,
                                                    const float* __restrict__ Wv,
                                                    const float* __restrict__ Wo,
                                                    u16* __restrict__ Wall,
                                                    u16* __restrict__ WoTp) {
  int i = blockIdx.x * 256 + threadIdx.x;
  if (i < 786432) {
    int c = i & 63;
    int r = (i >> 6) & 511;
    int panel = i >> 15;  // which*8 + b
    int which = panel >> 3, b = panel & 7;
    const float* W = which == 0 ? Wq : which == 1 ? Wk : Wv;
    float x = W[(b << 15) + r * 64 + c];
    size_t off = (size_t)panel * 32768 +
                 (size_t)((r >> 5) * 4 + (c >> 4)) * 512 +
                 ((((r & 31) >> 3) * 16) + (c & 15)) * 8 + (r & 7);
    Wall[off] = f2h(x);
  } else if (i < 786432 + 262144) {
    int rem = i - 786432;
    int c = rem & 511;
    int r = rem >> 9;
    float x = Wo[r * 512 + c];
    size_t off = (size_t)(c >> 6) * 32768 +
                 (size_t)((r >> 5) * 4 + ((c >> 4) & 3)) * 512 +
                 ((((r & 31) >> 3) * 16) + (c & 15)) * 8 + (r & 7);
    WoTp[off] = f2bf(x);
  }
}

// ------------- fused projection GEMM (fp16, 32 rows/wave, 3-slot pipeline) -------------
__global__ __launch_bounds__(256) void proj_gemm(const float* __restrict__ Q,
                                                 const float* __restrict__ Kin,
                                                 const float* __restrict__ Vin,
                                                 const u16* __restrict__ Wall,
                                                 u16* __restrict__ qh,
                                                 u16* __restrict__ khg,
                                                 u16* __restrict__ vsg) {
  const int n = 4096, K = 512, N = 64;
  int rb = blockIdx.x;
  int which = blockIdx.y >> 3, b = blockIdx.y & 7;
  int wave = threadIdx.x >> 6, lane = threadIdx.x & 63;
  int lr = lane & 15, lg = lane >> 4;
  int row0 = rb * 128 + wave * 32;

  const float* A = which == 0 ? Q : which == 1 ? Kin : Vin;
  const u16* Bp = Wall + (size_t)(which * 8 + b) * 32768 + lane * 8;
  const float* Ar0 = A + (size_t)(row0 + lr) * K + lg * 8;
  const float* Ar1 = Ar0 + (size_t)16 * K;

  f32x4 acc[2][4] = {};

  float4 ax[3][4];
  f16x8 bw[3][4];
#pragma unroll
  for (int p = 0; p < 3; ++p) {
    ax[p][0] = *(const float4*)(Ar0 + p * 32);
    ax[p][1] = *(const float4*)(Ar0 + p * 32 + 4);
    ax[p][2] = *(const float4*)(Ar1 + p * 32);
    ax[p][3] = *(const float4*)(Ar1 + p * 32 + 4);
#pragma unroll
    for (int ct = 0; ct < 4; ++ct)
      bw[p][ct] = *(const f16x8*)(Bp + (p * 4 + ct) * 512);
  }

#pragma unroll
  for (int ks = 0; ks < 16; ++ks) {
    int s = ks % 3;
    f16x8 ah0, al0, ah1, al1;
    split8_f16(ax[s][0], ax[s][1], ah0, al0);
    split8_f16(ax[s][2], ax[s][3], ah1, al1);
    if (ks < 13) {
      ax[s][0] = *(const float4*)(Ar0 + (ks + 3) * 32);
      ax[s][1] = *(const float4*)(Ar0 + (ks + 3) * 32 + 4);
      ax[s][2] = *(const float4*)(Ar1 + (ks + 3) * 32);
      ax[s][3] = *(const float4*)(Ar1 + (ks + 3) * 32 + 4);
    }
#pragma unroll
    for (int ct = 0; ct < 4; ++ct) {
      acc[0][ct] = __builtin_amdgcn_mfma_f32_16x16x32_f16(ah0, bw[s][ct], acc[0][ct], 0, 0, 0);
      acc[0][ct] = __builtin_amdgcn_mfma_f32_16x16x32_f16(al0, bw[s][ct], acc[0][ct], 0, 0, 0);
      acc[1][ct] = __builtin_amdgcn_mfma_f32_16x16x32_f16(ah1, bw[s][ct], acc[1][ct], 0, 0, 0);
      acc[1][ct] = __builtin_amdgcn_mfma_f32_16x16x32_f16(al1, bw[s][ct], acc[1][ct], 0, 0, 0);
    }
    if (ks < 13) {
#pragma unroll
      for (int ct = 0; ct < 4; ++ct)
        bw[s][ct] = *(const f16x8*)(Bp + ((ks + 3) * 4 + ct) * 512);
    }
  }

  const float QSCALE = 0.125f * 1.44269504f;  // 1/sqrt(64) * log2(e)
#pragma unroll
  for (int b2 = 0; b2 < 2; ++b2)
#pragma unroll
    for (int ct = 0; ct < 4; ++ct)
#pragma unroll
      for (int r = 0; r < 4; ++r) {
        float v = acc[b2][ct][r];
        int row = row0 + b2 * 16 + lg * 4 + r;
        int col = ct * 16 + lr;
        if (which == 2) {
          size_t byte = ((size_t)b * 64 + (row >> 6)) * 8192 +
                        SWZ(col, 2 * sigma64(row & 63));
          *(u16*)((char*)vsg + byte) = f2bf(v);
        } else if (which == 1) {
          size_t byte = ((size_t)b * 64 + (row >> 6)) * 8192 + SWZ(row & 63, col * 2);
          *(u16*)((char*)khg + byte) = f2h(v);
        } else {
          qh[((size_t)b * n + row) * N + col] = f2h(v * QSCALE);
        }
      }
}

// ---------------- flash attention: 4 waves x 32 q-rows, split-KV x4 ----------------
// (R13 internals restored) 32KB double buffer, one barrier/tile, m in log2
// units, l via MFMA ones-column, defer-rescale threshold 8.
__global__ __launch_bounds__(256, 4) void attn_kernel(const u16* __restrict__ qh,
                                                      const u16* __restrict__ khg,
                                                      const u16* __restrict__ vsg,
                                                      u16* __restrict__ Opart,
                                                      float2* __restrict__ ml) {
  const int n = 4096, d = 64;
  int bid = blockIdx.x;
  int j = bid & 7, w = bid >> 3;
  int grp = j * 4 + (w >> 5);  // = h*4 + part; all blocks of grp share bid%8
  int qb = w & 31;
  int h = grp >> 2, part = grp & 3;
  int wave = threadIdx.x >> 6, lane = threadIdx.x & 63;
  int c = lane & 15, g = lane >> 4;

  __shared__ char SB[32768];  // [KH0 8K][KH1 8K][VS0 8K][VS1 8K]

  int qrow0 = qb * 128 + wave * 32;
  f16x8 qf[2][2];
#pragma unroll
  for (int b2 = 0; b2 < 2; ++b2)
#pragma unroll
    for (int ks = 0; ks < 2; ++ks) {
      size_t qoff = ((size_t)h * n + qrow0 + b2 * 16 + c) * d + ks * 32 + g * 8;
      qf[b2][ks] = *(const f16x8*)(qh + qoff);
    }

  int koff[4][2];
#pragma unroll
  for (int ct = 0; ct < 4; ++ct)
#pragma unroll
    for (int ks = 0; ks < 2; ++ks)
      koff[ct][ks] = SWZ(ct * 16 + c, ks * 64 + g * 16);

  union { unsigned w[4]; bf16x8 v; } ones;
  ones.w[0] = 0x3f803f80u; ones.w[1] = 0x3f803f80u;
  ones.w[2] = 0x3f803f80u; ones.w[3] = 0x3f803f80u;

  f32x4 accO[2][4] = {};
  f32x4 accL[2] = {};
  float m[2] = {-INFINITY, -INFINITY};

  const char* khB = (const char*)khg + ((size_t)h * 64 + part * 16) * 8192;
  const char* vsB = (const char*)vsg + ((size_t)h * 64 + part * 16) * 8192;
  int so = wave * 2048;
  int sg = so + lane * 16;

#define STAGE(tile, BUF)                                            \
  do {                                                              \
    const char* kg_ = khB + (size_t)(tile) * 8192 + sg;             \
    const char* vg_ = vsB + (size_t)(tile) * 8192 + sg;             \
    char* kd_ = SB + (BUF)*8192 + so;                               \
    char* vd_ = SB + 16384 + (BUF)*8192 + so;                       \
    GLOAD16(kg_, kd_);                                              \
    GLOAD16(kg_ + 1024, kd_ + 1024);                                \
    GLOAD16(vg_, vd_);                                              \
    GLOAD16(vg_ + 1024, vd_ + 1024);                                \
  } while (0)

#define TILE(IT, CUR)                                                          \
  do {                                                                         \
    asm volatile("s_waitcnt vmcnt(0)" ::: "memory");                           \
    __builtin_amdgcn_s_barrier();                                              \
    asm volatile("" ::: "memory");                                             \
    if ((IT) < 15) STAGE((IT) + 1, 1 - (CUR));                                 \
    f32x4 s[2][4] = {};                                                        \
    __builtin_amdgcn_s_setprio(1);                                             \
    _Pragma("unroll") for (int ct = 0; ct < 4; ++ct) {                         \
      _Pragma("unroll") for (int ks = 0; ks < 2; ++ks) {                       \
        f16x8 kf = *(const f16x8*)(SB + (CUR)*8192 + koff[ct][ks]);            \
        s[0][ct] = __builtin_amdgcn_mfma_f32_16x16x32_f16(kf, qf[0][ks],       \
                                                          s[0][ct], 0, 0, 0);  \
        s[1][ct] = __builtin_amdgcn_mfma_f32_16x16x32_f16(kf, qf[1][ks],       \
                                                          s[1][ct], 0, 0, 0);  \
      }                                                                        \
    }                                                                          \
    __builtin_amdgcn_s_setprio(0);                                             \
    float mxv[2];                                                              \
    _Pragma("unroll") for (int b2 = 0; b2 < 2; ++b2) {                         \
      float t0 = MAX3(s[b2][0][0], s[b2][0][1], s[b2][0][2]);                  \
      float t1 = MAX3(s[b2][0][3], s[b2][1][0], s[b2][1][1]);                  \
      float t2 = MAX3(s[b2][1][2], s[b2][1][3], s[b2][2][0]);                  \
      float t3 = MAX3(s[b2][2][1], s[b2][2][2], s[b2][2][3]);                  \
      float t4 = MAX3(s[b2][3][0], s[b2][3][1], s[b2][3][2]);                  \
      mxv[b2] = fmaxf(MAX3(t0, t1, t2), MAX3(t3, t4, s[b2][3][3]));            \
    }                                                                          \
    _Pragma("unroll") for (int b2 = 0; b2 < 2; ++b2)                           \
        mxv[b2] = fmaxf(mxv[b2], __shfl_xor(mxv[b2], 16));                     \
    _Pragma("unroll") for (int b2 = 0; b2 < 2; ++b2)                           \
        mxv[b2] = fmaxf(mxv[b2], __shfl_xor(mxv[b2], 32));                     \
    _Pragma("unroll") for (int b2 = 0; b2 < 2; ++b2) {                         \
      bool need = mxv[b2] > m[b2] + 8.0f; /* defer-rescale threshold */        \
      float mn = need ? mxv[b2] : m[b2];                                       \
      _Pragma("unroll") for (int ct = 0; ct < 4; ++ct) {                       \
        s[b2][ct][0] = exp2a(s[b2][ct][0] - mn);                               \
        s[b2][ct][1] = exp2a(s[b2][ct][1] - mn);                               \
        s[b2][ct][2] = exp2a(s[b2][ct][2] - mn);                               \
        s[b2][ct][3] = exp2a(s[b2][ct][3] - mn);                               \
      }                                                                        \
      if (__any(need)) {                                                       \
        float alpha = exp2a(m[b2] - mn);                                       \
        m[b2] = mn;                                                            \
        _Pragma("unroll") for (int r = 0; r < 4; ++r) {                        \
          float ar = __shfl(alpha, g * 4 + r);                                 \
          accL[b2][r] *= ar;                                                   \
          _Pragma("unroll") for (int dt = 0; dt < 4; ++dt)                     \
              accO[b2][dt][r] *= ar;                                           \
        }                                                                      \
      }                                                                        \
    }                                                                          \
    union { unsigned w[4]; bf16x8 v; } pa[2][2];                               \
    _Pragma("unroll") for (int b2 = 0; b2 < 2; ++b2)                           \
        _Pragma("unroll") for (int ks = 0; ks < 2; ++ks) {                     \
      pa[b2][ks].w[0] = cvt_pk_bf16(s[b2][ks][0], s[b2][ks][1]);               \
      pa[b2][ks].w[1] = cvt_pk_bf16(s[b2][ks][2], s[b2][ks][3]);               \
      pa[b2][ks].w[2] = cvt_pk_bf16(s[b2][ks + 2][0], s[b2][ks + 2][1]);       \
      pa[b2][ks].w[3] = cvt_pk_bf16(s[b2][ks + 2][2], s[b2][ks + 2][3]);       \
    }                                                                          \
    __builtin_amdgcn_s_setprio(1);                                             \
    _Pragma("unroll") for (int dt = 0; dt < 4; ++dt) {                         \
      _Pragma("unroll") for (int ks = 0; ks < 2; ++ks) {                       \
        bf16x8 vf =                                                            \
            *(const bf16x8*)(SB + 16384 + (CUR)*8192 + koff[dt][ks]);          \
        accO[0][dt] = __builtin_amdgcn_mfma_f32_16x16x32_bf16(                 \
            pa[0][ks].v, vf, accO[0][dt], 0, 0, 0);                            \
        accO[1][dt] = __builtin_amdgcn_mfma_f32_16x16x32_bf16(                 \
            pa[1][ks].v, vf, accO[1][dt], 0, 0, 0);                            \
      }                                                                        \
    }                                                                          \
    accL[0] = __builtin_amdgcn_mfma_f32_16x16x32_bf16(pa[0][0].v, ones.v,      \
                                                      accL[0], 0, 0, 0);       \
    accL[0] = __builtin_amdgcn_mfma_f32_16x16x32_bf16(pa[0][1].v, ones.v,      \
                                                      accL[0], 0, 0, 0);       \
    accL[1] = __builtin_amdgcn_mfma_f32_16x16x32_bf16(pa[1][0].v, ones.v,      \
                                                      accL[1], 0, 0, 0);       \
    accL[1] = __builtin_amdgcn_mfma_f32_16x16x32_bf16(pa[1][1].v, ones.v,      \
                                                      accL[1], 0, 0, 0);       \
    __builtin_amdgcn_s_setprio(0);                                             \
  } while (0)

  STAGE(0, 0);
#pragma unroll 1
  for (int it2 = 0; it2 < 8; ++it2) {
    TILE(it2 * 2, 0);
    TILE(it2 * 2 + 1, 1);
  }
#undef TILE
#undef STAGE

  // epilogue: unnormalized O + (m,l); m in log2 units.
  u16* Ob = Opart + (((size_t)part * 8 + h) * n) * d;
  float2* mlp = ml + ((size_t)part * 8 + h) * n;
#pragma unroll
  for (int b2 = 0; b2 < 2; ++b2) {
#pragma unroll
    for (int r = 0; r < 4; ++r) {
      int row = qrow0 + b2 * 16 + g * 4 + r;
#pragma unroll
      for (int dt = 0; dt < 4; ++dt)
        Ob[(size_t)row * d + dt * 16 + c] = f2bf(accO[b2][dt][r]);
      float mrow = __shfl(m[b2], g * 4 + r);
      if (c == 0)
        mlp[qrow0 + b2 * 16 + g * 4 + r] = make_float2(mrow, accL[b2][r]);
    }
  }
}

// ---------------- combine the four KV parts (m in log2 units) ----------------
__global__ __launch_bounds__(256) void attn_combine(const u16* __restrict__ Opart,
                                                    const float2* __restrict__ ml,
                                                    u16* __restrict__ att) {
  int tid = blockIdx.x * 256 + threadIdx.x;
  int chunk = tid & 7;
  int h = (tid >> 3) & 7;
  int row = tid >> 6;
  float2 mls[4];
  float mstar = -INFINITY;
#pragma unroll
  for (int p = 0; p < 4; ++p) {
    mls[p] = ml[((size_t)p * 8 + h) * 4096 + row];
    mstar = fmaxf(mstar, mls[p].x);
  }
  float w[4], denom = 0.f;
#pragma unroll
  for (int p = 0; p < 4; ++p) {
    w[p] = exp2a(mls[p].x - mstar);
    denom += mls[p].y * w[p];
  }
  float inv = 1.f / denom;
  float res[8] = {};
#pragma unroll
  for (int p = 0; p < 4; ++p) {
    bf16x8 o = *(const bf16x8*)(Opart + (((size_t)p * 8 + h) * 4096 + row) * 64 + chunk * 8);
    float wp = w[p] * inv;
#pragma unroll
    for (int jj = 0; jj < 8; ++jj) res[jj] += bf2f((u16)o[jj]) * wp;
  }
  bf16x8 rv;
#pragma unroll
  for (int jj = 0; jj < 8; ++jj) rv[jj] = (short)f2bf(res[jj]);
  *(bf16x8*)(att + (size_t)row * 512 + h * 64 + chunk * 8) = rv;
}

// ------- final projection: out = att @ Wo (fp32 out), 4-slot prefetch -------
__global__ __launch_bounds__(256) void final_gemm(const u16* __restrict__ A,
                                                  const u16* __restrict__ BTp,
                                                  float* __restrict__ out,
                                                  int M, int K, int N) {
  int rb = blockIdx.x, cb = blockIdx.y;
  int wave = threadIdx.x >> 6, lane = threadIdx.x & 63;
  int lr = lane & 15, lg = lane >> 4;
  int row0 = rb * 64 + wave * 16;

  const u16* Arow = A + (size_t)(row0 + lr) * K + lg * 8;
  const u16* Bp = BTp + (size_t)cb * 32768 + lane * 8;

  f32x4 acc[4] = {};
  bf16x8 a[4];
  bf16x8 bb[4][4];
#pragma unroll
  for (int p = 0; p < 4; ++p) {
    a[p] = *(const bf16x8*)(Arow + p * 32);
#pragma unroll
    for (int ct = 0; ct < 4; ++ct)
      bb[p][ct] = *(const bf16x8*)(Bp + (p * 4 + ct) * 512);
  }

#pragma unroll
  for (int ks = 0; ks < 16; ++ks) {
    int s = ks & 3;
#pragma unroll
    for (int ct = 0; ct < 4; ++ct)
      acc[ct] = __builtin_amdgcn_mfma_f32_16x16x32_bf16(a[s], bb[s][ct], acc[ct], 0, 0, 0);
    if (ks < 12) {
      a[s] = *(const bf16x8*)(Arow + (ks + 4) * 32);
#pragma unroll
      for (int ct = 0; ct < 4; ++ct)
        bb[s][ct] = *(const bf16x8*)(Bp + ((ks + 4) * 4 + ct) * 512);
    }
  }
#pragma unroll
  for (int ct = 0; ct < 4; ++ct)
#pragma unroll
    for (int r = 0; r < 4; ++r)
      out[(size_t)(row0 + lg * 4 + r) * N + cb * 64 + ct * 16 + lr] = acc[ct][r];
}

// ---------------- launch ----------------
extern "C" void kernel_launch(void* const* d_in, const int* in_sizes, int n_in,
                              void* d_out, int out_size, void* d_ws, size_t ws_size,
                              hipStream_t stream) {
  const float* Q = (const float*)d_in[0];
  const float* K = (const float*)d_in[1];
  const float* V = (const float*)d_in[2];
  const float* Wq = (const float*)d_in[3];
  const float* Wk = (const float*)d_in[4];
  const float* Wv = (const float*)d_in[5];
  const float* Wo = (const float*)d_in[6];
  float* out = (float*)d_out;

  const int n = 4096, dim = 512;
  const size_t KB = 1 << 10, MB = 1 << 20;
  char* ws = (char*)d_ws;
  u16* qh     = (u16*)(ws + 0 * MB);   // 4 MB, fp16 (pre-scaled log2e/8)
  u16* khg    = (u16*)(ws + 4 * MB);   // 4 MB, fp16 swizzled images
  u16* vsg    = (u16*)(ws + 8 * MB);   // 4 MB, bf16 swizzled sigma-permuted
  u16* Opart  = (u16*)(ws + 12 * MB);  // 16 MB (4 parts) -> ends 28 MB
  u16* Wall   = (u16*)(ws + 12 * MB);  // 1.5 MB fp16, inside Opart (dead by attn)
  float2* ml  = (float2*)(ws + 28 * MB);          // 1 MB
  u16* WoTp   = (u16*)(ws + 29 * MB);             // 512 KB -> peak 29.5 MB
  u16* att    = khg;  // khg dead after attn; combine writes att here

  prep_weights<<<4096, 256, 0, stream>>>(Wq, Wk, Wv, Wo, Wall, WoTp);

  proj_gemm<<<dim3(32, 24), 256, 0, stream>>>(Q, K, V, Wall, qh, khg, vsg);

  attn_kernel<<<1024, 256, 0, stream>>>(qh, khg, vsg, Opart, ml);
  attn_combine<<<(n * 8 * 8) / 256, 256, 0, stream>>>(Opart, ml, att);

  final_gemm<<<dim3(n / 64, dim / 64), 256, 0, stream>>>(att, WoTp, out, n, dim, dim);
}